// Round 7
// baseline (476.430 us; speedup 1.0000x reference)
//
#include <hip/hip_runtime.h>

// Problem constants
#define NB 96
#define NQ 96
#define NV 197
#define NT 77
#define DK 768
#define DE 512

typedef __attribute__((ext_vector_type(8))) short s16x8;
typedef __attribute__((ext_vector_type(4))) float f32x4;

__device__ __forceinline__ unsigned short f2bf(float f) {
  union { float f; unsigned int u; } v; v.f = f;
  unsigned int u = v.u;
  unsigned int r = u + 0x7fffu + ((u >> 16) & 1u);
  return (unsigned short)(r >> 16);
}

__device__ __forceinline__ unsigned int pack2bf(float a, float b) {
  return (unsigned int)f2bf(a) | ((unsigned int)f2bf(b) << 16);
}

// global -> LDS direct, 16B/lane.  LDS dest = uniform base + lane*16.
// off must be a compile-time constant (13-bit signed, bytes).
#define GL16(gp, lp, off)                                                \
  __builtin_amdgcn_global_load_lds(                                      \
      (const __attribute__((address_space(1))) void*)(gp),               \
      (__attribute__((address_space(3))) void*)(lp), 16, (off), 0)

// ---------------------------------------------------------------------------
// K_prep: fused  cvt(Wv) | cvt(Wt) | cls_v | cls_t   via blockIdx ranges.
// (unchanged — passed in R4)
// ---------------------------------------------------------------------------
__global__ __launch_bounds__(256) void prep_kernel(
    const float* __restrict__ Wv_tok, unsigned short* __restrict__ Wvb,
    const float* __restrict__ Wt_tok, unsigned short* __restrict__ Wtb,
    const float* __restrict__ visual_cls, const float* __restrict__ Wv_cls,
    const float* __restrict__ bv_cls, float* __restrict__ v_cls_o,
    const float* __restrict__ textual_cls, const float* __restrict__ Wt_cls,
    const float* __restrict__ bt_cls, float* __restrict__ t_cls_o) {
  __shared__ float xs[DK];
  const int blk = blockIdx.x;
  const int tid = threadIdx.x;

  if (blk < 768) {
    const float* src = (blk < 384) ? Wv_tok : Wt_tok;
    unsigned short* dst = (blk < 384) ? Wvb : Wtb;
    int i = ((blk < 384) ? blk : (blk - 384)) * 256 + tid;
    float4 x = ((const float4*)src)[i];
    ushort4 h;
    h.x = f2bf(x.x); h.y = f2bf(x.y); h.z = f2bf(x.z); h.w = f2bf(x.w);
    ((ushort4*)dst)[i] = h;
    return;
  }
  const int is_t = (blk >= 864);
  const int row = blk - (is_t ? 864 : 768);
  const float* X = is_t ? textual_cls : visual_cls;
  const float* W = is_t ? Wt_cls : Wv_cls;
  const float* bias = is_t ? bt_cls : bv_cls;
  float* out = is_t ? t_cls_o : v_cls_o;

  const float* xr = X + (long)row * DK;
  for (int i = tid; i < DK; i += 256) xs[i] = xr[i];
  __syncthreads();
  for (int c = tid; c < DE; c += 256) {
    const float* wr = W + (long)c * DK;
    float s = 0.f;
    #pragma unroll 4
    for (int k = 0; k < DK; k += 4) {
      float4 w4 = *(const float4*)(wr + k);
      s += xs[k] * w4.x + xs[k + 1] * w4.y + xs[k + 2] * w4.z + xs[k + 3] * w4.w;
    }
    out[(long)row * DE + c] = s + bias[c];
  }
}

// ---------------------------------------------------------------------------
// K_proj: 32-row version (suspect-under-test, from R5/R6).
// Blocks 0..590 -> visual (18912 rows); 591..821 -> textual (7392 rows).
// Block = 32 rows x 512 cols.  K-chunk 32, 24 iters.
// ---------------------------------------------------------------------------
__global__ __launch_bounds__(256, 2) void proj_norm_kernel(
    const float* __restrict__ Xv, const unsigned short* __restrict__ Wvb,
    const float* __restrict__ bv, unsigned short* __restrict__ Yv,
    const float* __restrict__ Xt, const unsigned short* __restrict__ Wtb,
    const float* __restrict__ bt, unsigned short* __restrict__ Yt) {
  __shared__ __align__(16) unsigned short Ws[512 * 32];  // 32768 B
  __shared__ __align__(16) unsigned short Xs[32 * 32];   // 2048 B
  __shared__ float ssq_lds[4][32];

  const int blk = blockIdx.x;
  const int is_t = (blk >= 591);
  const float* X = is_t ? Xt : Xv;
  const unsigned short* Wb = is_t ? Wtb : Wvb;
  const float* bias = is_t ? bt : bv;
  unsigned short* Y = is_t ? Yt : Yv;
  const int M = is_t ? (NQ * NT) : (NB * NV);
  const long row0 = (long)(is_t ? (blk - 591) : blk) * 32;

  const int tid = threadIdx.x;
  const int wave = tid >> 6;
  const int lane = tid & 63;
  const int l15 = lane & 15;
  const int quad = lane >> 4;

  // W staging: seg s = j*4 + wave (j=0..7); row = wave*16 + (lane>>2) + j*64
  const int wr4 = lane >> 2;                 // 0..15
  const int wseg = lane & 3;
  const unsigned short* pw_base =
      Wb + (long)(wave * 16 + wr4) * DK + ((wseg ^ (wr4 & 3)) << 3);

  // X staging: threads 0..127: row = tid>>2 (0..31), seg = tid&3
  const int xrow = tid >> 2;
  const int xseg = tid & 3;
  long grx = row0 + (xrow & 31); if (grx > M - 1) grx = M - 1;
  const float* px = X + grx * DK + xseg * 8;
  const int xaddr = ((xrow & 31) << 5) + ((xseg ^ (xrow & 3)) << 3);

  f32x4 acc[2][8];
  #pragma unroll
  for (int m = 0; m < 2; ++m)
    #pragma unroll
    for (int n = 0; n < 8; ++n)
      acc[m][n] = (f32x4){0.f, 0.f, 0.f, 0.f};

  for (int kc = 0; kc < DK; kc += 32) {
    __syncthreads();
    if (tid < 128) {  // stage X (fp32 -> bf16, 16B ds_write)
      float4 x0 = *(const float4*)px;
      float4 x1 = *(const float4*)(px + 4);
      uint4 h;
      h.x = pack2bf(x0.x, x0.y); h.y = pack2bf(x0.z, x0.w);
      h.z = pack2bf(x1.x, x1.y); h.w = pack2bf(x1.z, x1.w);
      *(uint4*)(&Xs[xaddr]) = h;
    }
    px += 32;
    {  // stage W: 8 GL16/thread
      const unsigned short* pw = pw_base;
      #pragma unroll
      for (int j = 0; j < 8; ++j) {
        GL16(pw, &Ws[(j * 4 + wave) << 9], 0);
        pw += 64 * DK;
      }
      pw_base += 32;
    }
    __syncthreads();
    s16x8 af[2];
    #pragma unroll
    for (int mi = 0; mi < 2; ++mi) {
      int arow = mi * 16 + l15;
      af[mi] = *(const s16x8*)&Xs[(arow << 5) + ((quad ^ (arow & 3)) << 3)];
    }
    #pragma unroll
    for (int nt = 0; nt < 8; ++nt) {
      int wrow = wave * 128 + nt * 16 + l15;
      s16x8 bfr = *(const s16x8*)&Ws[(wrow << 5) + ((quad ^ (wrow & 3)) << 3)];
      #pragma unroll
      for (int mi = 0; mi < 2; ++mi)
        acc[mi][nt] = __builtin_amdgcn_mfma_f32_16x16x32_bf16(af[mi], bfr, acc[mi][nt], 0, 0, 0);
    }
  }

  #pragma unroll
  for (int nt = 0; nt < 8; ++nt) {
    float bc = bias[wave * 128 + nt * 16 + l15];
    #pragma unroll
    for (int mi = 0; mi < 2; ++mi) {
      acc[mi][nt].x += bc; acc[mi][nt].y += bc; acc[mi][nt].z += bc; acc[mi][nt].w += bc;
    }
  }

  #pragma unroll
  for (int mi = 0; mi < 2; ++mi)
    #pragma unroll
    for (int r = 0; r < 4; ++r) {
      float t = 0.f;
      #pragma unroll
      for (int nt = 0; nt < 8; ++nt) { float v = acc[mi][nt][r]; t += v * v; }
      t += __shfl_xor(t, 1);
      t += __shfl_xor(t, 2);
      t += __shfl_xor(t, 4);
      t += __shfl_xor(t, 8);
      if (l15 == 0) ssq_lds[wave][mi * 16 + quad * 4 + r] = t;
    }
  __syncthreads();

  #pragma unroll
  for (int mi = 0; mi < 2; ++mi) {
    #pragma unroll
    for (int r = 0; r < 4; ++r) {
      int rr = mi * 16 + quad * 4 + r;
      float tot = ssq_lds[0][rr] + ssq_lds[1][rr] + ssq_lds[2][rr] + ssq_lds[3][rr];
      float scale = 1.f / fmaxf(sqrtf(tot), 1e-12f);
      long grow = row0 + rr;
      if (grow < M) {
        #pragma unroll
        for (int nt = 0; nt < 8; ++nt) {
          int col = wave * 128 + nt * 16 + l15;
          Y[grow * DE + col] = f2bf(acc[mi][nt][r] * scale);
        }
      }
    }
  }
}

// ---------------------------------------------------------------------------
// K3: fused similarity + masked max/sum.  EXACT R4 version (passed).
// One block per (b, q-pair).  K-chunk 32, 16 unrolled iters:
//   __syncthreads -> stage(next buf, async GL16) -> compute(cur buf)
// ---------------------------------------------------------------------------
__global__ __launch_bounds__(256, 2) void score_kernel(
    const unsigned short* __restrict__ Yv, const unsigned short* __restrict__ Yt,
    const int* __restrict__ tlen, float* __restrict__ t2v, float* __restrict__ v2t) {
  __shared__ __align__(16) unsigned short As[2][104 * 64];  // 2 x 13312 B
  __shared__ __align__(16) unsigned short Bs[2][80 * 64];   // 2 x 10240 B
  __shared__ float colbuf[4][160];
  __shared__ float rowsum_lds[4][2];

  const int tid = threadIdx.x;
  const int wave = tid >> 6;
  const int lane = tid & 63;
  const int l15 = lane & 15;
  const int quad = lane >> 4;

  // XCD-locality swizzle: b fixed per XCD while qi sweeps.
  const int idx = blockIdx.x;
  const int span = idx / 384;          // 0..11
  const int r0 = idx - span * 384;
  const int b = span * 8 + (r0 & 7);
  const int qi = r0 >> 3;              // 0..47
  const int q0 = qi * 2;

  const unsigned short* Ab = Yv + (long)b * (NV * DE);
  const unsigned short* Bb = Yt + (long)q0 * (NT * DE);

  // ---- k-invariant staging pointers (pair-interleaved units) ----
  const int ul = lane >> 3;
  const int slot = lane & 7;
  const int kseg = ((slot >> 1) ^ (ul & 3)) << 3;  // element offset
  auto aptr = [&](int s) {
    int row = (s * 8 + ul) * 2 + (slot & 1);
    if (row > NV - 1) row = NV - 1;
    return Ab + row * DE + kseg;
  };
  auto bptr = [&](int s) {
    int r = (s * 8 + ul) * 2 + (slot & 1);
    int half = (r >= 80) ? 1 : 0;
    int t = r - 80 * half;
    if (t > NT - 1) t = NT - 1;
    return Bb + (long)half * (NT * DE) + t * DE + kseg;
  };

  // A segs (13): wave stages {w, w+4, w+8}; seg 12 by w0.
  // B segs (10): wave stages {w, w+4}; segs 8,9 by w0,w1.
  const unsigned short* pA[4];
  #pragma unroll
  for (int j = 0; j < 3; ++j) pA[j] = aptr(wave + j * 4);
  pA[3] = aptr(12);
  const unsigned short* pB[3];
  #pragma unroll
  for (int j = 0; j < 2; ++j) pB[j] = bptr(wave + j * 4);
  pB[2] = bptr(wave + 8);

  // ---- k-invariant LDS fragment offsets (elements) ----
  int aoff[4], boff[10];
  #pragma unroll
  for (int i = 0; i < 4; ++i) {
    int arow = (wave + i * 4) * 16 + l15;
    int u = arow >> 1;
    aoff[i] = (u << 6) + ((quad ^ (u & 3)) << 4) + ((arow & 1) << 3);
  }
  #pragma unroll
  for (int nt = 0; nt < 10; ++nt) {
    int brow = nt * 16 + l15;
    int u = brow >> 1;
    boff[nt] = (u << 6) + ((quad ^ (u & 3)) << 4) + ((brow & 1) << 3);
  }

  f32x4 acc[4][10];
  #pragma unroll
  for (int i = 0; i < 4; ++i)
    #pragma unroll
    for (int nt = 0; nt < 10; ++nt)
      acc[i][nt] = (f32x4){0.f, 0.f, 0.f, 0.f};

  auto do_compute = [&](int p) {
    s16x8 bf[10];
    #pragma unroll
    for (int nt = 0; nt < 10; ++nt)
      bf[nt] = *(const s16x8*)&Bs[p][boff[nt]];
    #pragma unroll
    for (int i = 0; i < 4; ++i) {
      int mt = wave + (i << 2);
      if (mt < 13) {
        s16x8 af = *(const s16x8*)&As[p][aoff[i]];
        #pragma unroll
        for (int nt = 0; nt < 10; ++nt)
          acc[i][nt] = __builtin_amdgcn_mfma_f32_16x16x32_bf16(af, bf[nt], acc[i][nt], 0, 0, 0);
      }
    }
  };

#define SCORE_STAGE(p, KB)                                               \
  {                                                                      \
    _Pragma("unroll")                                                    \
    for (int j = 0; j < 3; ++j)                                          \
      GL16(pA[j], &As[p][(wave + j * 4) << 9], KB);                      \
    if (wave == 0)                                                       \
      GL16(pA[3], &As[p][12 << 9], KB);                                  \
    _Pragma("unroll")                                                    \
    for (int j = 0; j < 2; ++j)                                          \
      GL16(pB[j], &Bs[p][(wave + j * 4) << 9], KB);                      \
    if (wave < 2)                                                        \
      GL16(pB[2], &Bs[p][(wave + 8) << 9], KB);                          \
  }

#define SCORE_ITER(cur, KB_NEXT)                                         \
  {                                                                      \
    __syncthreads();                                                     \
    if ((KB_NEXT) < 1024) SCORE_STAGE(1 - (cur), KB_NEXT);               \
    do_compute(cur);                                                     \
  }

  SCORE_STAGE(0, 0)       // prologue: chunk 0 -> buf 0
  SCORE_ITER(0, 64)
  SCORE_ITER(1, 128)
  SCORE_ITER(0, 192)
  SCORE_ITER(1, 256)
  SCORE_ITER(0, 320)
  SCORE_ITER(1, 384)
  SCORE_ITER(0, 448)
  SCORE_ITER(1, 512)
  SCORE_ITER(0, 576)
  SCORE_ITER(1, 640)
  SCORE_ITER(0, 704)
  SCORE_ITER(1, 768)
  SCORE_ITER(0, 832)
  SCORE_ITER(1, 896)
  SCORE_ITER(0, 960)
  SCORE_ITER(1, 1024)     // last: no stage

#undef SCORE_ITER
#undef SCORE_STAGE

  const int len0 = tlen[q0];
  const int len1 = tlen[q0 + 1];

  // ---- column max over valid v rows (t2v path), both q halves ----
  #pragma unroll
  for (int nt = 0; nt < 10; ++nt) {
    float m = -1e30f;
    #pragma unroll
    for (int i = 0; i < 4; ++i) {
      int mt = wave + (i << 2);
      if (mt < 13) {
        int mbase = mt * 16 + quad * 4;
        #pragma unroll
        for (int r = 0; r < 4; ++r)
          if (mbase + r < NV) m = fmaxf(m, acc[i][nt][r]);
      }
    }
    m = fmaxf(m, __shfl_xor(m, 16));
    m = fmaxf(m, __shfl_xor(m, 32));
    if (lane < 16) colbuf[wave][nt * 16 + l15] = m;
  }

  // ---- row max over valid t cols (v2t path), per q half ----
  float psum[2] = {0.f, 0.f};
  #pragma unroll
  for (int h = 0; h < 2; ++h) {
    int len = h ? len1 : len0;
    #pragma unroll
    for (int i = 0; i < 4; ++i) {
      int mt = wave + (i << 2);
      if (mt < 13) {
        int mbase = mt * 16 + quad * 4;
        #pragma unroll
        for (int r = 0; r < 4; ++r) {
          float rm = -1e30f;
          #pragma unroll
          for (int nt = 0; nt < 5; ++nt) {
            int c = nt * 16 + l15;
            if (c < len) rm = fmaxf(rm, acc[i][h * 5 + nt][r]);
          }
          rm = fmaxf(rm, __shfl_xor(rm, 1));
          rm = fmaxf(rm, __shfl_xor(rm, 2));
          rm = fmaxf(rm, __shfl_xor(rm, 4));
          rm = fmaxf(rm, __shfl_xor(rm, 8));
          if (len < NT) rm = fmaxf(rm, 0.f);  // masked zeros participate in max
          if (l15 == 0 && (mbase + r) < NV) psum[h] += rm;
        }
      }
    }
    psum[h] += __shfl_xor(psum[h], 16);
    psum[h] += __shfl_xor(psum[h], 32);
  }
  if (lane == 0) { rowsum_lds[wave][0] = psum[0]; rowsum_lds[wave][1] = psum[1]; }
  __syncthreads();

  if (wave < 2) {
    int q = q0 + wave;
    int len = wave ? len1 : len0;
    int cbase = wave * 80;
    float ssum = 0.f;
    for (int c = lane; c < 80; c += 64) {
      if (c < len) {
        float m = fmaxf(fmaxf(colbuf[0][cbase + c], colbuf[1][cbase + c]),
                        fmaxf(colbuf[2][cbase + c], colbuf[3][cbase + c]));
        ssum += m;
      }
    }
    ssum += __shfl_xor(ssum, 1);
    ssum += __shfl_xor(ssum, 2);
    ssum += __shfl_xor(ssum, 4);
    ssum += __shfl_xor(ssum, 8);
    ssum += __shfl_xor(ssum, 16);
    ssum += __shfl_xor(ssum, 32);
    if (lane == 0) {
      float rs = rowsum_lds[0][wave] + rowsum_lds[1][wave] +
                 rowsum_lds[2][wave] + rowsum_lds[3][wave];
      t2v[b * NQ + q] = ssum / (float)len;
      v2t[b * NQ + q] = rs / (float)NV;
    }
  }
}

// ---------------------------------------------------------------------------
extern "C" void kernel_launch(void* const* d_in, const int* in_sizes, int n_in,
                              void* d_out, int out_size, void* d_ws, size_t ws_size,
                              hipStream_t stream) {
  (void)in_sizes; (void)n_in; (void)out_size; (void)ws_size;
  const float* visual_cls     = (const float*)d_in[0];
  const float* visual_tokens  = (const float*)d_in[1];
  const float* textual_cls    = (const float*)d_in[2];
  const float* textual_tokens = (const float*)d_in[3];
  const float* Wv_cls = (const float*)d_in[4];
  const float* bv_cls = (const float*)d_in[5];
  const float* Wt_cls = (const float*)d_in[6];
  const float* bt_cls = (const float*)d_in[7];
  const float* Wv_tok = (const float*)d_in[8];
  const float* bv_tok = (const float*)d_in[9];
  const float* Wt_tok = (const float*)d_in[10];
  const float* bt_tok = (const float*)d_in[11];
  const int* text_length = (const int*)d_in[12];

  float* out = (float*)d_out;
  float* v_cls_o = out;
  float* t_cls_o = out + 49152;
  float* t2v_o   = out + 98304;
  float* v2t_o   = out + 107520;

  char* ws = (char*)d_ws;
  unsigned short* Wvb = (unsigned short*)(ws);
  unsigned short* Wtb = (unsigned short*)(ws + 786432);
  unsigned short* Yv  = (unsigned short*)(ws + 1572864);
  unsigned short* Yt  = (unsigned short*)(ws + 20938752);

  prep_kernel<<<960, 256, 0, stream>>>(
      Wv_tok, Wvb, Wt_tok, Wtb,
      visual_cls, Wv_cls, bv_cls, v_cls_o,
      textual_cls, Wt_cls, bt_cls, t_cls_o);

  proj_norm_kernel<<<822, 256, 0, stream>>>(
      visual_tokens, Wvb, bv_tok, Yv,
      textual_tokens, Wtb, bt_tok, Yt);

  score_kernel<<<(NB * NQ) / 2, 256, 0, stream>>>(Yv, Yt, text_length, t2v_o, v2t_o);
}